// Round 18
// baseline (210.637 us; speedup 1.0000x reference)
//
#include <hip/hip_runtime.h>
#include <math.h>
#include <float.h>

#define D_DIM 768
#define K_C   256
#define KC    32
#define NCH   24
#define BMR   256
#define NTHR  1024
#define MARGIN 1.5e-2f
#define M0SHIFT 39.0f

typedef __attribute__((ext_vector_type(8))) short s16x8;
typedef __attribute__((ext_vector_type(4))) float f32x4;

__device__ inline unsigned short f2bf(float x) {      // RNE f32 -> bf16 bits
    unsigned u = __float_as_uint(x);
    unsigned r = 0x7FFFu + ((u >> 16) & 1u);
    return (unsigned short)((u + r) >> 16);
}
__device__ inline int swz(int row, int slot) {        // 16B-granule swizzle
    return row*32 + (((slot ^ (row >> 1)) & 3) << 3);
}
__device__ inline void gl_lds16(const void* g, void* l) {
    __builtin_amdgcn_global_load_lds(
        (const __attribute__((address_space(1))) void*)g,
        (__attribute__((address_space(3))) void*)l, 16, 0, 0);
}
__device__ inline unsigned pk2(float a, float b) {    // trunc-bf16 pair pack
    return __builtin_amdgcn_perm(__float_as_uint(b), __float_as_uint(a), 0x07060302u);
}

// ---------------- prep: c2 (f64) + C image + zero accumulators ----------------
__global__ __launch_bounds__(256) void kprep(const float* __restrict__ C,
    short* __restrict__ Cimg, float* __restrict__ c2f,
    float* __restrict__ g1, float* __restrict__ g2, int* __restrict__ done)
{
    const int k = blockIdx.x;
    const int t = threadIdx.x;
    __shared__ double red[4];
    double s = 0.0;
#pragma unroll
    for (int i = 0; i < 3; ++i) {
        int d = t + 256*i;
        float x = C[(size_t)k*D_DIM + d];
        s += (double)x * (double)x;
        int ch = d >> 5, g = (d & 31) >> 3, e = d & 7;
        Cimg[(size_t)ch*8192 + swz(k, g) + e] = (short)f2bf(x);
    }
#pragma unroll
    for (int m = 1; m < 64; m <<= 1) s += __shfl_xor(s, m, 64);
    if ((t & 63) == 0) red[t >> 6] = s;
    __syncthreads();
    if (t == 0) {
        c2f[k] = (float)(red[0] + red[1] + red[2] + red[3]);
        g1[k] = 0.f; g2[k] = 0.f;
        if (k == 0) *done = 0;
    }
}

// load one chunk of E for this lane's two rows (4x float4, stays in regs)
#define EQ4(Q0,Q1,Q2,Q3,CH) do {                                        \
        const float* e0_ = Ep0 + (CH)*KC;                               \
        const float* e1_ = Ep1 + (CH)*KC;                               \
        Q0 = *reinterpret_cast<const float4*>(e0_);                     \
        Q1 = *reinterpret_cast<const float4*>(e0_ + 4);                 \
        Q2 = *reinterpret_cast<const float4*>(e1_);                     \
        Q3 = *reinterpret_cast<const float4*>(e1_ + 4);                 \
    } while (0)

// convert regs -> A-frags (lane=row, sgr=octet), accumulate e2, run 16 MFMA
#define CVMM(Q0,Q1,Q2,Q3,CB) do {                                       \
        e2p0 = fmaf(Q0.x,Q0.x,e2p0); e2p0 = fmaf(Q0.y,Q0.y,e2p0);       \
        e2p0 = fmaf(Q0.z,Q0.z,e2p0); e2p0 = fmaf(Q0.w,Q0.w,e2p0);       \
        e2p0 = fmaf(Q1.x,Q1.x,e2p0); e2p0 = fmaf(Q1.y,Q1.y,e2p0);       \
        e2p0 = fmaf(Q1.z,Q1.z,e2p0); e2p0 = fmaf(Q1.w,Q1.w,e2p0);       \
        e2p1 = fmaf(Q2.x,Q2.x,e2p1); e2p1 = fmaf(Q2.y,Q2.y,e2p1);       \
        e2p1 = fmaf(Q2.z,Q2.z,e2p1); e2p1 = fmaf(Q2.w,Q2.w,e2p1);       \
        e2p1 = fmaf(Q3.x,Q3.x,e2p1); e2p1 = fmaf(Q3.y,Q3.y,e2p1);       \
        e2p1 = fmaf(Q3.z,Q3.z,e2p1); e2p1 = fmaf(Q3.w,Q3.w,e2p1);       \
        uint4 HA, HB;                                                   \
        HA.x = pk2(Q0.x,Q0.y); HA.y = pk2(Q0.z,Q0.w);                   \
        HA.z = pk2(Q1.x,Q1.y); HA.w = pk2(Q1.z,Q1.w);                   \
        HB.x = pk2(Q2.x,Q2.y); HB.y = pk2(Q2.z,Q2.w);                   \
        HB.z = pk2(Q3.x,Q3.y); HB.w = pk2(Q3.z,Q3.w);                   \
        s16x8 a0 = *reinterpret_cast<s16x8*>(&HA);                      \
        s16x8 a1 = *reinterpret_cast<s16x8*>(&HB);                      \
        _Pragma("unroll")                                               \
        for (int n_ = 0; n_ < 8; ++n_) {                                \
            s16x8 bh_ = *reinterpret_cast<const s16x8*>((CB) + boff[n_]); \
            acc[0][n_] = __builtin_amdgcn_mfma_f32_16x16x32_bf16(a0, bh_, acc[0][n_], 0, 0, 0); \
            acc[1][n_] = __builtin_amdgcn_mfma_f32_16x16x32_bf16(a1, bh_, acc[1][n_], 0, 0, 0); \
        }                                                               \
    } while (0)

#define CSTAGE3(PH,DST) do {                                            \
        const char* img_ = (const char*)Cimg + (size_t)(PH)*49152;      \
        gl_lds16(img_ + t*16,           (DST) + t*16);                  \
        gl_lds16(img_ + 16384 + t*16,   (DST) + 16384 + t*16);          \
        gl_lds16(img_ + 32768 + t*16,   (DST) + 32768 + t*16);          \
    } while (0)

#define WAITBAR(N) do {                                                 \
        asm volatile("s_waitcnt vmcnt(" #N ") lgkmcnt(0)" ::: "memory");\
        __builtin_amdgcn_s_barrier();                                   \
        __builtin_amdgcn_sched_barrier(0);                              \
    } while (0)

// one phase: 3 chunks from CUR; prefetch C(PH+1)->NXT and E(first of PH+1)
#define PHASE_FULL(SA0,SA1,SA2,SA3, SB0,SB1,SB2,SB3, PH, CUR, NXT) do { \
        CSTAGE3((PH)+1, NXT);                                           \
        __builtin_amdgcn_sched_barrier(0);                              \
        EQ4(SB0,SB1,SB2,SB3, (PH)*3 + 1);                               \
        CVMM(SA0,SA1,SA2,SA3, (CUR));                                   \
        EQ4(SA0,SA1,SA2,SA3, (PH)*3 + 2);                               \
        CVMM(SB0,SB1,SB2,SB3, (CUR) + 16384);                           \
        EQ4(SB0,SB1,SB2,SB3, ((PH)+1)*3);                               \
        CVMM(SA0,SA1,SA2,SA3, (CUR) + 32768);                           \
        WAITBAR(4);                                                     \
    } while (0)

// ---- fused kernel: GEMM + argmin + inline f64 refine + softmin + final ----
__global__ __launch_bounds__(NTHR, 4) void kdist(const float* __restrict__ E,
    const float* __restrict__ Cf, const short* __restrict__ Cimg,
    const float* __restrict__ c2f, float* __restrict__ labels,
    float* __restrict__ g1, float* __restrict__ g2,
    int* __restrict__ done, float* __restrict__ out)
{
    __shared__ __align__(16) char lds[98304];
    // Cb0@0 (48KB), Cb1@49152 (48KB)
    // epilogue overlay on Cb0 (valid after final WAITBAR(0)):
    float*  e2s   = (float*)lds;                     // [256] 1KB
    float*  spart = (float*)(lds + 1024);            // [8][256][2] 16KB
    float4* topb  = (float4*)(lds + 17408);          // [2][256] 8KB
    int*    qcnt  = (int*)(lds + 25600);
    int4*   qlist = (int4*)(lds + 25616);            // [256] 4KB
    int*    lastf = (int*)(lds + 29712);
    float*  fred  = (float*)(lds + 29728);           // [4]

    const int t    = threadIdx.x;
    const int lane = t & 63;
    const int w    = t >> 6;                         // 0..15
    const int wm   = w >> 1, wn = w & 1;             // row-32-group(8) / col-half(2)
    const int c4   = lane & 15, sgr = lane >> 4;
    const int R0   = blockIdx.x * BMR;

    f32x4 acc[2][8];
#pragma unroll
    for (int m = 0; m < 2; ++m)
#pragma unroll
        for (int n = 0; n < 8; ++n) acc[m][n] = (f32x4){0.f,0.f,0.f,0.f};

    // per-lane E pointers: rows wm*32+c4 (m=0) and +16 (m=1), k-octet sgr
    const float* Ep0 = E + (size_t)(R0 + wm*32 + c4)*D_DIM + sgr*8;
    const float* Ep1 = Ep0 + (size_t)16*D_DIM;
    int boff[8];
#pragma unroll
    for (int n = 0; n < 8; ++n) boff[n] = 2*swz(wn*128 + n*16 + c4, sgr);
    float e2p0 = 0.f, e2p1 = 0.f;
    float4 qa0, qa1, qa2, qa3, qb0, qb1, qb2, qb3;

    // ---- prologue: C(phase0)->Cb0, E(chunk0)->qa ----
    CSTAGE3(0, lds);
    __builtin_amdgcn_sched_barrier(0);
    EQ4(qa0, qa1, qa2, qa3, 0);
    WAITBAR(4);                       // C(0) landed; qa in flight

    // ---- phases 0..5 as 3 pairs ----
#pragma unroll 1
    for (int pp = 0; pp < 3; ++pp) {
        const int ph = 2*pp;
        PHASE_FULL(qa0,qa1,qa2,qa3, qb0,qb1,qb2,qb3, ph,     lds,         lds + 49152);
        PHASE_FULL(qb0,qb1,qb2,qb3, qa0,qa1,qa2,qa3, ph + 1, lds + 49152, lds);
    }
    // ---- phase 6 (prefetches phase 7) ----
    PHASE_FULL(qa0,qa1,qa2,qa3, qb0,qb1,qb2,qb3, 6, lds, lds + 49152);
    // ---- phase 7 (chunks 21,22,23 from Cb1; no prefetch) ----
    {
        char* cur = lds + 49152;
        EQ4(qa0,qa1,qa2,qa3, 22);
        CVMM(qb0,qb1,qb2,qb3, cur);
        EQ4(qb0,qb1,qb2,qb3, 23);
        CVMM(qa0,qa1,qa2,qa3, cur + 16384);
        CVMM(qb0,qb1,qb2,qb3, cur + 32768);
        WAITBAR(0);
    }

    // ---- e2 per row-pair: reduce over k-octets (sgr); write overlay ----
    {
        float a = e2p0 + __shfl_xor(e2p0, 16, 64);
        a += __shfl_xor(a, 32, 64);
        float b = e2p1 + __shfl_xor(e2p1, 16, 64);
        b += __shfl_xor(b, 32, 64);
        if (lane < 16 && wn == 0) {
            e2s[wm*32 + c4]      = a;
            e2s[wm*32 + 16 + c4] = b;
        }
        if (t == 0) *qcnt = 0;
    }
    __syncthreads();

    float e2r[2][4];
#pragma unroll
    for (int m = 0; m < 2; ++m)
#pragma unroll
        for (int g = 0; g < 4; ++g)
            e2r[m][g] = e2s[wm*32 + m*16 + sgr*4 + g];
    float c2v[8];
#pragma unroll
    for (int n = 0; n < 8; ++n) c2v[n] = c2f[wn*128 + n*16 + c4];

    // dot -> dist
#pragma unroll
    for (int m = 0; m < 2; ++m)
#pragma unroll
        for (int n = 0; n < 8; ++n) {
            f32x4 v = acc[m][n];
#pragma unroll
            for (int g = 0; g < 4; ++g) {
                float d2 = fmaf(-2.f, v[g], e2r[m][g] + c2v[n]);
                v[g] = sqrtf(fmaxf(d2, 0.f));
            }
            acc[m][n] = v;
        }

    // ---- top-3 via centered packed keys ----
#pragma unroll
    for (int m = 0; m < 2; ++m)
#pragma unroll
        for (int g = 0; g < 4; ++g) {
            float k1 = FLT_MAX, k2 = FLT_MAX, k3 = FLT_MAX;
#pragma unroll
            for (int n = 0; n < 8; ++n) {
                unsigned idx = (unsigned)(wn*128 + n*16 + c4);
                unsigned u = __float_as_uint(acc[m][n][g]);
                float kd = __uint_as_float(((u - idx + 127u) & 0xFFFFFF00u) | idx);
                if (kd < k1)      { k3 = k2; k2 = k1; k1 = kd; }
                else if (kd < k2) { k3 = k2; k2 = kd; }
                else if (kd < k3) { k3 = kd; }
            }
#pragma unroll
            for (int msk = 1; msk < 16; msk <<= 1) {
                float o1 = __shfl_xor(k1, msk, 64);
                float o2 = __shfl_xor(k2, msk, 64);
                float o3 = __shfl_xor(k3, msk, 64);
                float m1 = fminf(k1, o1), M1 = fmaxf(k1, o1);
                float m2 = fminf(k2, o2), M2 = fmaxf(k2, o2);
                float r3 = fminf(k3, o3);
                k1 = m1;
                k2 = fminf(M1, m2);
                k3 = fminf(fmaxf(M1, m2), fminf(M2, r3));
            }
            if (c4 == 0)
                topb[wn*BMR + wm*32 + m*16 + sgr*4 + g] = (float4){k1, k2, k3, 0.f};
        }

    // ---- softmin partials, fixed shift ----
#pragma unroll
    for (int n = 0; n < 8; ++n) {
        float s1 = 0.f, s2 = 0.f;
#pragma unroll
        for (int m = 0; m < 2; ++m)
#pragma unroll
            for (int g = 0; g < 4; ++g) {
                float d = acc[m][n][g];
                float wgt = __expf(M0SHIFT - d);
                s1 += wgt; s2 = fmaf(d, wgt, s2);
            }
        s1 += __shfl_xor(s1, 16, 64); s2 += __shfl_xor(s2, 16, 64);
        s1 += __shfl_xor(s1, 32, 64); s2 += __shfl_xor(s2, 32, 64);
        if (lane < 16) {
            int cc = wn*128 + n*16 + c4;
            float* p = &spart[(size_t)(wm*K_C + cc)*2];
            p[0] = s1; p[1] = s2;
        }
    }
    __syncthreads();

    if (t < BMR) {
        float4 a = topb[t], b = topb[BMR + t];
        float m1 = fminf(a.x, b.x), M1 = fmaxf(a.x, b.x);
        float m2 = fminf(a.y, b.y), M2 = fmaxf(a.y, b.y);
        float r3 = fminf(a.z, b.z);
        float k1 = m1, k2 = fminf(M1, m2), k3 = fminf(fmaxf(M1, m2), fminf(M2, r3));
        unsigned u1 = __float_as_uint(k1), u2 = __float_as_uint(k2), u3 = __float_as_uint(k3);
        int i1 = (int)(u1 & 255u), i2 = (int)(u2 & 255u), i3 = (int)(u3 & 255u);
        float v1 = __uint_as_float(u1 & 0xFFFFFF00u);
        float v2 = __uint_as_float(u2 & 0xFFFFFF00u);
        int row = R0 + t;
        labels[row] = (float)i1;
        if (v2 - v1 < MARGIN) {                   // each row enqueues at most once
            int slot = atomicAdd(qcnt, 1);
            qlist[slot] = make_int4(row, i1, i2, i3);
        }
    }
    if (t < K_C) {
        float s1 = 0.f, s2 = 0.f;
#pragma unroll
        for (int q = 0; q < 8; ++q) {
            s1 += spart[(size_t)(q*K_C + t)*2];
            s2 += spart[(size_t)(q*K_C + t)*2 + 1];
        }
        atomicAdd(&g1[t], s1);
        atomicAdd(&g2[t], s2);
    }
    __syncthreads();

    // ---- inline f64 refinement: one wave per flagged row ----
    const int nq = *qcnt;
    for (int e = w; e < nq; e += 16) {
        int4 q = qlist[e];
        const int row = q.x, k1 = q.y, k2 = q.z, k3 = q.w;
        double s1 = 0, s2 = 0, s3 = 0;
#pragma unroll 1
        for (int d = lane; d < D_DIM; d += 64) {
            double ed = (double)E[(size_t)row*D_DIM + d];
            double ca = (double)Cf[(size_t)k1*D_DIM + d];
            double cb = (double)Cf[(size_t)k2*D_DIM + d];
            double cc = (double)Cf[(size_t)k3*D_DIM + d];
            s1 += ca*(ca - 2.0*ed);       // e^2 cancels in compare
            s2 += cb*(cb - 2.0*ed);
            s3 += cc*(cc - 2.0*ed);
        }
#pragma unroll
        for (int msk = 32; msk; msk >>= 1) {
            s1 += __shfl_down(s1, msk, 64);
            s2 += __shfl_down(s2, msk, 64);
            s3 += __shfl_down(s3, msk, 64);
        }
        if (lane == 0) {
            double bv = s1; int bk = k1;
            if (s2 < bv || (s2 == bv && k2 < bk)) { bv = s2; bk = k2; }
            if (s3 < bv || (s3 == bv && k3 < bk)) { bv = s3; bk = k3; }
            labels[row] = (float)bk;
        }
    }

    // ---- last-block-done finalization: loss = mean_c g2/g1 ----
    __syncthreads();
    if (t == 0) {
        __threadfence();
        *lastf = (atomicAdd(done, 1) == (int)gridDim.x - 1) ? 1 : 0;
    }
    __syncthreads();
    if (*lastf) {
        float v = 0.f;
        if (t < K_C) {
            float a = atomicAdd(&g1[t], 0.f);    // coherent device-scope read
            float b = atomicAdd(&g2[t], 0.f);
            v = b / a;
        }
#pragma unroll
        for (int msk = 1; msk < 64; msk <<= 1) v += __shfl_xor(v, msk, 64);
        if (lane == 0 && w < 4) fred[w] = v;
        __syncthreads();
        if (t == 0) out[0] = (fred[0] + fred[1] + fred[2] + fred[3]) / 256.0f;
    }
}

extern "C" void kernel_launch(void* const* d_in, const int* in_sizes, int n_in,
                              void* d_out, int out_size, void* d_ws, size_t ws_size,
                              hipStream_t stream)
{
    const float* E = (const float*)d_in[0];
    const float* C = (const float*)d_in[1];
    float* out = (float*)d_out;

    const int Bn = in_sizes[0] / D_DIM;      // 65536
    const int NB = Bn / BMR;                 // 256

    char* ws = (char*)d_ws;
    float* c2f  = (float*)ws;                                      // 1 KB
    float* g1   = (float*)(ws + 1024);                             // 1 KB
    float* g2   = (float*)(ws + 2048);                             // 1 KB
    int*   done = (int*)(ws + 3072);
    short* Cimg = (short*)(ws + 4096);                             // 384 KB
    float* labels = out + 1;

    kprep <<<K_C, 256, 0, stream>>>(C, Cimg, c2f, g1, g2, done);
    kdist <<<NB,  NTHR, 0, stream>>>(E, C, Cimg, c2f, labels, g1, g2, done, out);
}

// Round 19
// 79.926 us; speedup vs baseline: 2.6354x; 2.6354x over previous
//
#include <hip/hip_runtime.h>
#include <math.h>
#include <float.h>

#define D_DIM 768
#define K_C   256
#define KC    32
#define NCH   24
#define BMR   256
#define NTHR  1024
#define MARGIN 1.5e-2f
#define M0SHIFT 39.0f

typedef __attribute__((ext_vector_type(8))) short s16x8;
typedef __attribute__((ext_vector_type(4))) float f32x4;

__device__ inline unsigned short f2bf(float x) {      // RNE f32 -> bf16 bits
    unsigned u = __float_as_uint(x);
    unsigned r = 0x7FFFu + ((u >> 16) & 1u);
    return (unsigned short)((u + r) >> 16);
}
__device__ inline int swz(int row, int slot) {        // 16B-granule swizzle
    return row*32 + (((slot ^ (row >> 1)) & 3) << 3);
}
__device__ inline void gl_lds16(const void* g, void* l) {
    __builtin_amdgcn_global_load_lds(
        (const __attribute__((address_space(1))) void*)g,
        (__attribute__((address_space(3))) void*)l, 16, 0, 0);
}
__device__ inline unsigned pk2(float a, float b) {    // trunc-bf16 pair pack
    return __builtin_amdgcn_perm(__float_as_uint(b), __float_as_uint(a), 0x07060302u);
}

// ---------------- prep: c2 (f64) + C image + zero accumulators ----------------
__global__ __launch_bounds__(256) void kprep(const float* __restrict__ C,
    short* __restrict__ Cimg, float* __restrict__ c2f,
    float* __restrict__ g1, float* __restrict__ g2, int* __restrict__ done)
{
    const int k = blockIdx.x;
    const int t = threadIdx.x;
    __shared__ double red[4];
    double s = 0.0;
#pragma unroll
    for (int i = 0; i < 3; ++i) {
        int d = t + 256*i;
        float x = C[(size_t)k*D_DIM + d];
        s += (double)x * (double)x;
        int ch = d >> 5, g = (d & 31) >> 3, e = d & 7;
        Cimg[(size_t)ch*8192 + swz(k, g) + e] = (short)f2bf(x);
    }
#pragma unroll
    for (int m = 1; m < 64; m <<= 1) s += __shfl_xor(s, m, 64);
    if ((t & 63) == 0) red[t >> 6] = s;
    __syncthreads();
    if (t == 0) {
        c2f[k] = (float)(red[0] + red[1] + red[2] + red[3]);
        g1[k] = 0.f; g2[k] = 0.f;
        if (k == 0) *done = 0;
    }
}

// E convert: trunc-bf16, accumulate e2
#define ECONV_M(Q0,Q1,EHI) do {                                         \
        e2p = fmaf(Q0.x,Q0.x,e2p); e2p = fmaf(Q0.y,Q0.y,e2p);           \
        e2p = fmaf(Q0.z,Q0.z,e2p); e2p = fmaf(Q0.w,Q0.w,e2p);           \
        e2p = fmaf(Q1.x,Q1.x,e2p); e2p = fmaf(Q1.y,Q1.y,e2p);           \
        e2p = fmaf(Q1.z,Q1.z,e2p); e2p = fmaf(Q1.w,Q1.w,e2p);           \
        uint4 Ha;                                                       \
        Ha.x = pk2(Q0.x,Q0.y); Ha.y = pk2(Q0.z,Q0.w);                   \
        Ha.z = pk2(Q1.x,Q1.y); Ha.w = pk2(Q1.z,Q1.w);                   \
        *reinterpret_cast<uint4*>((EHI) + ebyte) = Ha;                  \
    } while (0)

#define MFMA_M(EB,CB) do {                                              \
        s16x8 ah_[4];                                                   \
        _Pragma("unroll")                                               \
        for (int m_ = 0; m_ < 4; ++m_)                                  \
            ah_[m_] = *reinterpret_cast<const s16x8*>((EB) + aoff[m_]); \
        _Pragma("unroll")                                               \
        for (int n_ = 0; n_ < 4; ++n_) {                                \
            s16x8 bh_ = *reinterpret_cast<const s16x8*>((CB) + boff[n_]); \
            _Pragma("unroll")                                           \
            for (int m_ = 0; m_ < 4; ++m_)                              \
                acc[m_][n_] = __builtin_amdgcn_mfma_f32_16x16x32_bf16(ah_[m_], bh_, acc[m_][n_], 0, 0, 0); \
        }                                                               \
    } while (0)

#define CSTAGE_M(CHI,DST) do {                                          \
        const char* img_ = (const char*)Cimg + (size_t)(CHI)*16384;     \
        gl_lds16(img_ + t*16, (DST) + t*16);                            \
    } while (0)

#define WAITBAR(N) do {                                                 \
        asm volatile("s_waitcnt vmcnt(" #N ") lgkmcnt(0)" ::: "memory");\
        __builtin_amdgcn_s_barrier();                                   \
        __builtin_amdgcn_sched_barrier(0);                              \
    } while (0)

#define EQLOAD(QV0,QV1,CHI) do {                                        \
        const float* ep_ = Ep + (CHI)*KC;                               \
        QV0 = *reinterpret_cast<const float4*>(ep_);                    \
        QV1 = *reinterpret_cast<const float4*>(ep_ + 4);                \
    } while (0)

// ---- fused kernel: GEMM + argmin + inline f64 refine + softmin + final ----
__global__ __launch_bounds__(NTHR, 4) void kdist(const float* __restrict__ E,
    const float* __restrict__ Cf, const short* __restrict__ Cimg,
    const float* __restrict__ c2f, float* __restrict__ labels,
    float* __restrict__ g1, float* __restrict__ g2,
    int* __restrict__ done, float* __restrict__ out)
{
    __shared__ __align__(16) char lds[65536];
    // Eb0@0 (16KB), Eb1@16384, Cb0@32768 (16KB), Cb1@49152
    // epilogue overlay (E region, valid after final __syncthreads):
    float*  e2s   = (float*)lds;                     // [256] 1KB
    float*  spart = (float*)(lds + 1024);            // [4][256][2] 8KB
    float4* topb  = (float4*)(lds + 9216);           // [4][256] 16KB
    int*    qcnt  = (int*)(lds + 25600);
    int4*   qlist = (int4*)(lds + 25616);            // [256] 4KB
    int*    lastf = (int*)(lds + 29712);
    float*  fred  = (float*)(lds + 29728);           // [4]

    const int t    = threadIdx.x;
    const int lane = t & 63;
    const int w    = t >> 6;                         // 0..15
    const int wm   = w >> 2, wn = w & 3;             // row-quarter(64) / col-quarter(64)
    const int c4   = lane & 15, sgr = lane >> 4;
    const int R0   = blockIdx.x * BMR;

    f32x4 acc[4][4];
#pragma unroll
    for (int m = 0; m < 4; ++m)
#pragma unroll
        for (int n = 0; n < 4; ++n) acc[m][n] = (f32x4){0.f,0.f,0.f,0.f};

    const int erow = t >> 2, eseg = t & 3;           // 256 rows x 4 segs
    const float* Ep = E + (size_t)(R0 + erow)*D_DIM + eseg*8;
    const int ebyte = 2*swz(erow, eseg);
    int aoff[4], boff[4];
#pragma unroll
    for (int m = 0; m < 4; ++m) aoff[m] = 2*swz(wm*64 + m*16 + c4, sgr);
#pragma unroll
    for (int n = 0; n < 4; ++n) boff[n] = 2*swz(wn*64 + n*16 + c4, sgr);
    float e2p = 0.f;
    float4 qa0, qa1, qb0, qb1;

    // ---- prologue ----
    CSTAGE_M(0, lds + 32768);
    __builtin_amdgcn_sched_barrier(0);
    EQLOAD(qa0, qa1, 0);
    ECONV_M(qa0, qa1, lds);          // waits qa -> C(0) landed too
    EQLOAD(qb0, qb1, 1);
    asm volatile("s_waitcnt lgkmcnt(0)" ::: "memory");
    __builtin_amdgcn_s_barrier();
    __builtin_amdgcn_sched_barrier(0);

    // ---- 11 steady pairs (chunks 0..21) ----
#pragma unroll 1
    for (int pr = 0; pr < 11; ++pr) {
        const int ch = 2*pr;
        CSTAGE_M(ch + 1, lds + 49152);
        __builtin_amdgcn_sched_barrier(0);
        EQLOAD(qa0, qa1, ch + 2);
        MFMA_M(lds, lds + 32768);
        ECONV_M(qb0, qb1, lds + 16384);  // E(ch+1), loaded one barrier ago
        WAITBAR(2);
        CSTAGE_M(ch + 2, lds + 32768);
        __builtin_amdgcn_sched_barrier(0);
        EQLOAD(qb0, qb1, ch + 3);
        MFMA_M(lds + 16384, lds + 49152);
        ECONV_M(qa0, qa1, lds);          // E(ch+2)
        WAITBAR(2);
    }
    // ---- peeled chunks 22, 23 ----
    CSTAGE_M(23, lds + 49152);
    __builtin_amdgcn_sched_barrier(0);
    MFMA_M(lds, lds + 32768);
    ECONV_M(qb0, qb1, lds + 16384);      // E(23)
    WAITBAR(0);
    MFMA_M(lds + 16384, lds + 49152);
    __syncthreads();

    // ---- e2 per row (4 threads/row); zero refine queue ----
    {
        float es = e2p + __shfl_xor(e2p, 1, 64);
        es += __shfl_xor(es, 2, 64);
        if ((t & 3) == 0) e2s[t >> 2] = es;
        if (t == 0) *qcnt = 0;
    }
    __syncthreads();

    float e2r[4][4];
#pragma unroll
    for (int m = 0; m < 4; ++m)
#pragma unroll
        for (int g = 0; g < 4; ++g)
            e2r[m][g] = e2s[wm*64 + m*16 + sgr*4 + g];
    float c2v[4];
#pragma unroll
    for (int n = 0; n < 4; ++n) c2v[n] = c2f[wn*64 + n*16 + c4];

    // dot -> dist
#pragma unroll
    for (int m = 0; m < 4; ++m)
#pragma unroll
        for (int n = 0; n < 4; ++n) {
            f32x4 v = acc[m][n];
#pragma unroll
            for (int g = 0; g < 4; ++g) {
                float d2 = fmaf(-2.f, v[g], e2r[m][g] + c2v[n]);
                v[g] = sqrtf(fmaxf(d2, 0.f));
            }
            acc[m][n] = v;
        }

    // ---- top-3 via centered packed keys (err ±4.9e-4, idx-independent) ----
#pragma unroll
    for (int m = 0; m < 4; ++m)
#pragma unroll
        for (int g = 0; g < 4; ++g) {
            float k1 = FLT_MAX, k2 = FLT_MAX, k3 = FLT_MAX;
#pragma unroll
            for (int n = 0; n < 4; ++n) {
                unsigned idx = (unsigned)(wn*64 + n*16 + c4);
                unsigned u = __float_as_uint(acc[m][n][g]);
                float kd = __uint_as_float(((u - idx + 127u) & 0xFFFFFF00u) | idx);
                if (kd < k1)      { k3 = k2; k2 = k1; k1 = kd; }
                else if (kd < k2) { k3 = k2; k2 = kd; }
                else if (kd < k3) { k3 = kd; }
            }
#pragma unroll
            for (int msk = 1; msk < 16; msk <<= 1) {
                float o1 = __shfl_xor(k1, msk, 64);
                float o2 = __shfl_xor(k2, msk, 64);
                float o3 = __shfl_xor(k3, msk, 64);
                float m1 = fminf(k1, o1), M1 = fmaxf(k1, o1);
                float m2 = fminf(k2, o2), M2 = fmaxf(k2, o2);
                float r3 = fminf(k3, o3);
                k1 = m1;
                k2 = fminf(M1, m2);
                k3 = fminf(fmaxf(M1, m2), fminf(M2, r3));
            }
            if (c4 == 0)
                topb[wn*BMR + wm*64 + m*16 + sgr*4 + g] = (float4){k1, k2, k3, 0.f};
        }

    // ---- softmin partials, fixed shift ----
#pragma unroll
    for (int n = 0; n < 4; ++n) {
        float s1 = 0.f, s2 = 0.f;
#pragma unroll
        for (int m = 0; m < 4; ++m)
#pragma unroll
            for (int g = 0; g < 4; ++g) {
                float d = acc[m][n][g];
                float wgt = __expf(M0SHIFT - d);
                s1 += wgt; s2 = fmaf(d, wgt, s2);
            }
        s1 += __shfl_xor(s1, 16, 64); s2 += __shfl_xor(s2, 16, 64);
        s1 += __shfl_xor(s1, 32, 64); s2 += __shfl_xor(s2, 32, 64);
        if (lane < 16) {
            int cc = wn*64 + n*16 + c4;
            float* p = &spart[(size_t)(wm*K_C + cc)*2];
            p[0] = s1; p[1] = s2;
        }
    }
    __syncthreads();

    if (t < BMR) {
        float4 q0 = topb[t],           q1 = topb[BMR + t];
        float4 q2 = topb[2*BMR + t],   q3 = topb[3*BMR + t];
#define MRG3(A1,A2,A3,B1,B2,B3,R1,R2,R3) do {                           \
        float m1_ = fminf(A1,B1), M1_ = fmaxf(A1,B1);                   \
        float m2_ = fminf(A2,B2), M2_ = fmaxf(A2,B2);                   \
        float r3_ = fminf(A3,B3);                                       \
        R1 = m1_; R2 = fminf(M1_, m2_);                                 \
        R3 = fminf(fmaxf(M1_, m2_), fminf(M2_, r3_)); } while (0)
        float a1, a2, a3, b1, b2, b3, k1, k2, k3;
        MRG3(q0.x,q0.y,q0.z, q1.x,q1.y,q1.z, a1,a2,a3);
        MRG3(q2.x,q2.y,q2.z, q3.x,q3.y,q3.z, b1,b2,b3);
        MRG3(a1,a2,a3, b1,b2,b3, k1,k2,k3);
#undef MRG3
        unsigned u1 = __float_as_uint(k1), u2 = __float_as_uint(k2), u3 = __float_as_uint(k3);
        int i1 = (int)(u1 & 255u), i2 = (int)(u2 & 255u), i3 = (int)(u3 & 255u);
        float v1 = __uint_as_float(u1 & 0xFFFFFF00u);
        float v2 = __uint_as_float(u2 & 0xFFFFFF00u);
        int row = R0 + t;
        labels[row] = (float)i1;
        if (v2 - v1 < MARGIN) {                   // each row enqueues at most once
            int slot = atomicAdd(qcnt, 1);
            qlist[slot] = make_int4(row, i1, i2, i3);
        }
    }
    if (t < K_C) {
        float s1 = 0.f, s2 = 0.f;
#pragma unroll
        for (int q = 0; q < 4; ++q) {
            s1 += spart[(size_t)(q*K_C + t)*2];
            s2 += spart[(size_t)(q*K_C + t)*2 + 1];
        }
        atomicAdd(&g1[t], s1);
        atomicAdd(&g2[t], s2);
    }
    __syncthreads();

    // ---- inline f64 refinement: one wave per flagged row ----
    const int nq = *qcnt;
    for (int e = w; e < nq; e += 16) {
        int4 q = qlist[e];
        const int row = q.x, k1 = q.y, k2 = q.z, k3 = q.w;
        double s1 = 0, s2 = 0, s3 = 0;
#pragma unroll 1
        for (int d = lane; d < D_DIM; d += 64) {
            double ed = (double)E[(size_t)row*D_DIM + d];
            double ca = (double)Cf[(size_t)k1*D_DIM + d];
            double cb = (double)Cf[(size_t)k2*D_DIM + d];
            double cc = (double)Cf[(size_t)k3*D_DIM + d];
            s1 += ca*(ca - 2.0*ed);       // e^2 cancels in compare
            s2 += cb*(cb - 2.0*ed);
            s3 += cc*(cc - 2.0*ed);
        }
#pragma unroll
        for (int msk = 32; msk; msk >>= 1) {
            s1 += __shfl_down(s1, msk, 64);
            s2 += __shfl_down(s2, msk, 64);
            s3 += __shfl_down(s3, msk, 64);
        }
        if (lane == 0) {
            double bv = s1; int bk = k1;
            if (s2 < bv || (s2 == bv && k2 < bk)) { bv = s2; bk = k2; }
            if (s3 < bv || (s3 == bv && k3 < bk)) { bv = s3; bk = k3; }
            labels[row] = (float)bk;
        }
    }

    // ---- last-block-done finalization: loss = mean_c g2/g1 ----
    __syncthreads();
    if (t == 0) {
        __threadfence();
        *lastf = (atomicAdd(done, 1) == (int)gridDim.x - 1) ? 1 : 0;
    }
    __syncthreads();
    if (*lastf) {
        float v = 0.f;
        if (t < K_C) {
            float a = atomicAdd(&g1[t], 0.f);    // coherent device-scope read
            float b = atomicAdd(&g2[t], 0.f);
            v = b / a;
        }
#pragma unroll
        for (int msk = 1; msk < 64; msk <<= 1) v += __shfl_xor(v, msk, 64);
        if (lane == 0 && w < 4) fred[w] = v;
        __syncthreads();
        if (t == 0) out[0] = (fred[0] + fred[1] + fred[2] + fred[3]) / 256.0f;
    }
}

extern "C" void kernel_launch(void* const* d_in, const int* in_sizes, int n_in,
                              void* d_out, int out_size, void* d_ws, size_t ws_size,
                              hipStream_t stream)
{
    const float* E = (const float*)d_in[0];
    const float* C = (const float*)d_in[1];
    float* out = (float*)d_out;

    const int Bn = in_sizes[0] / D_DIM;      // 65536
    const int NB = Bn / BMR;                 // 256

    char* ws = (char*)d_ws;
    float* c2f  = (float*)ws;                                      // 1 KB
    float* g1   = (float*)(ws + 1024);                             // 1 KB
    float* g2   = (float*)(ws + 2048);                             // 1 KB
    int*   done = (int*)(ws + 3072);
    short* Cimg = (short*)(ws + 4096);                             // 384 KB
    float* labels = out + 1;

    kprep <<<K_C, 256, 0, stream>>>(C, Cimg, c2f, g1, g2, done);
    kdist <<<NB,  NTHR, 0, stream>>>(E, C, Cimg, c2f, labels, g1, g2, done, out);
}